// Round 11
// baseline (102.128 us; speedup 1.0000x reference)
//
#include <hip/hip_runtime.h>
#include <hip/hip_bf16.h>

// Problem geometry (fixed by reference config)
#define IN_F   4096
#define OUT_F  12288
#define OUT_PG 4096
#define M_ROWS 1024     // 2*512
#define R2     32       // GROUPS * R = 2*16
#define KS     16       // k-split factor (Tpart partials in d_ws)

// ---------------- Kernel A: Tpart[ks][m][r] = sum_{k in slice} x[m][k]*wA[r][k] ----
// Grid: (KS=16, 64) x 256 thr = 1024 blocks. Block = 4 waves x 4 rows = 16 rows,
// k-slice = 256 (single chunk, single sync). Stage wA chunk (32 KB) in LDS
// (coalesced); inner loop: 32 ds_read_b128, each feeding 4 rows x 4 FMA.
// Butterfly tree-reduce -> 2 coalesced 256B stores/wave. (Zero-fill moved to R.)
__global__ __launch_bounds__(256) void lora_a_kernel(
    const float* __restrict__ x, const float* __restrict__ wA,
    float* __restrict__ Tpart) {
  constexpr int SLICE = IN_F / KS;          // 256
  __shared__ float As[R2 * SLICE];          // 32 KB

  const int t = threadIdx.x;
  const int l = t & 63;
  const int w = t >> 6;                     // wave id
  const int ks = blockIdx.x;
  const int row0 = blockIdx.y * 16 + w * 4;
  const int kb = ks * SLICE;

  // Stage 32x256 wA chunk: flat f = r*256+kk, 8 float4 per thread, coalesced.
#pragma unroll
  for (int i = 0; i < 8; ++i) {
    const int f = t * 4 + i * 1024;
    const int r = f >> 8, kk = f & 255;
    *reinterpret_cast<float4*>(&As[f]) =
        *reinterpret_cast<const float4*>(&wA[r * IN_F + kb + kk]);
  }
  __syncthreads();

  float4 xv[4];
#pragma unroll
  for (int m = 0; m < 4; ++m)
    xv[m] = *reinterpret_cast<const float4*>(&x[(row0 + m) * IN_F + kb + l * 4]);

  float acc[4][32];
#pragma unroll
  for (int m = 0; m < 4; ++m)
#pragma unroll
    for (int r = 0; r < 32; ++r) acc[m][r] = 0.f;

#pragma unroll
  for (int r = 0; r < 32; ++r) {
    const float4 av = *reinterpret_cast<const float4*>(&As[r * SLICE + l * 4]);
#pragma unroll
    for (int m = 0; m < 4; ++m)
      acc[m][r] += xv[m].x * av.x + xv[m].y * av.y + xv[m].z * av.z + xv[m].w * av.w;
  }

  // Butterfly tree-reduce per row: after masked steps + xor-32 merge, every
  // lane holds the full sum for r = l&31.
  float v[4];
#pragma unroll
  for (int m2 = 0; m2 < 4; ++m2) {
#pragma unroll
    for (int m = 16; m >= 1; m >>= 1) {
#pragma unroll
      for (int i = 0; i < m; ++i) {
        const float a = acc[m2][i], b = acc[m2][i + m];
        const float mine   = (l & m) ? b : a;
        const float theirs = (l & m) ? a : b;
        acc[m2][i] = mine + __shfl_xor(theirs, m, 64);
      }
    }
    v[m2] = acc[m2][0] + __shfl_xor(acc[m2][0], 32, 64);
  }
  // Row pair p: lanes 0..31 -> row0+2p, lanes 32..63 -> row0+2p+1 (256B/store).
#pragma unroll
  for (int p = 0; p < 2; ++p) {
    const float outv = (l < 32) ? v[2 * p] : v[2 * p + 1];
    Tpart[(ks * M_ROWS + row0 + 2 * p + (l >> 5)) * R2 + (l & 31)] = outv;
  }
}

// ---------------- Kernel R: T[m][r] = sum_ks Tpart[ks][m][r]; zero middle block ----
// Grid: 256 blocks x 256 thr. Block owns 4 rows. 8-way ks split (2 loads/thread)
// + LDS reduce. Also writes the disabled middle output block's zeros for its
// rows (64 KB/block, coalesced 1KB wave-stores) -- overlaps the load latency.
__global__ __launch_bounds__(256) void lora_r_kernel(
    const float* __restrict__ Tpart, float* __restrict__ T,
    float* __restrict__ out) {
  const int t = threadIdx.x;
  const int row0 = blockIdx.x * 4;

  // Zero-fill middle block: rows row0..+4, cols OUT_PG..2*OUT_PG.
  {
    const float4 z = {0.f, 0.f, 0.f, 0.f};
    const int zr = row0 + (t >> 6);
    const int c0 = OUT_PG + (t & 63) * 4;
#pragma unroll
    for (int i = 0; i < 16; ++i)
      *reinterpret_cast<float4*>(&out[zr * OUT_F + c0 + i * 256]) = z;
  }

  // Reduce partials: 32 f4 elems (4 rows x 8 r-quads), 8-way ks split.
  __shared__ float4 red[32][8];
  const int e   = t >> 3;            // 0..31: elem index
  const int ksl = t & 7;             // 0..7
  const int row = row0 + (e >> 3);
  const int q   = (e & 7) * 4;
  const float4 v0 = *reinterpret_cast<const float4*>(
      &Tpart[((ksl + 0) * M_ROWS + row) * R2 + q]);
  const float4 v1 = *reinterpret_cast<const float4*>(
      &Tpart[((ksl + 8) * M_ROWS + row) * R2 + q]);
  red[e][ksl] = {v0.x + v1.x, v0.y + v1.y, v0.z + v1.z, v0.w + v1.w};
  __syncthreads();
  if (t < 32) {
    float4 s = red[t][0];
#pragma unroll
    for (int i = 1; i < 8; ++i) {
      const float4 v = red[t][i];
      s.x += v.x; s.y += v.y; s.z += v.z; s.w += v.w;
    }
    *reinterpret_cast<float4*>(&T[(row0 + (t >> 3)) * R2 + (t & 7) * 4]) = s;
  }
}

// ---------------- Kernel B: out[m][col] = sum_r T[m][g*16+r] * wB[col][r] ----------
// Covers ONLY the two LoRA-enabled output blocks (middle block zeroed by R).
// Grid: (32, 32) x 256 thr = 1024 blocks (4/CU). Block tile 32 rows x 256 cols.
// bx<16 -> group 0 (out cols 0..4096); bx>=16 -> group 1 (out cols 8192..12288).
// wB tile staged TRANSPOSED in LDS; T tile (final, one f4 load/thread) in LDS,
// broadcast reads; per-thread 8 rows x 4 cols, coalesced f4 stores.
__global__ __launch_bounds__(256) void lora_b_kernel(
    const float* __restrict__ T, const float* __restrict__ wB,
    float* __restrict__ out) {
  const int t = threadIdx.x;
  const int bx = blockIdx.x;            // 0..31
  const int by = blockIdx.y;            // 0..31
  const int g = bx >> 4;                // 0,1
  const int jbase = (bx & 15) << 8;     // within-group col base
  const int colbase = g ? (2 * OUT_PG + jbase) : jbase;
  const int rbase = by << 5;            // 32 rows
  const int cq = t & 63;                // col quad
  const int rowg = t >> 6;              // wave id (uniform)

  __shared__ float BsT[16 * 260];       // [r][col], stride 260 (pad 4)
  __shared__ float Ts[32 * 16];

  // Stage wB^T: 256 cols x 16 r = 1024 f4, 4 per thread; coalesced global reads.
#pragma unroll
  for (int i = 0; i < 4; ++i) {
    const int idx = t + i * 256;
    const int c = idx >> 2, r0 = (idx & 3) * 4;
    const float4 v = *reinterpret_cast<const float4*>(
        &wB[(g * OUT_PG + jbase + c) * 16 + r0]);
    BsT[(r0 + 0) * 260 + c] = v.x;
    BsT[(r0 + 1) * 260 + c] = v.y;
    BsT[(r0 + 2) * 260 + c] = v.z;
    BsT[(r0 + 3) * 260 + c] = v.w;
  }
  // Stage T tile: one coalesced f4 load per thread (T is L2/L3-resident).
  if (t < 128) {
    const int row = t >> 2, q = t & 3;
    *reinterpret_cast<float4*>(&Ts[row * 16 + q * 4]) =
        *reinterpret_cast<const float4*>(&T[(rbase + row) * R2 + g * 16 + q * 4]);
  }
  __syncthreads();

  // Per-thread B: brow[r] = B values of this thread's 4 cols at rank r.
  float4 brow[16];
#pragma unroll
  for (int r = 0; r < 16; ++r)
    brow[r] = *reinterpret_cast<const float4*>(&BsT[r * 260 + cq * 4]);

#pragma unroll
  for (int rr = 0; rr < 8; ++rr) {
    const int rowl = rowg * 8 + rr;
    float ts[16];
#pragma unroll
    for (int q = 0; q < 4; ++q)
      *reinterpret_cast<float4*>(&ts[q * 4]) =
          *reinterpret_cast<const float4*>(&Ts[rowl * 16 + q * 4]);  // broadcast
    float a0 = 0.f, a1 = 0.f, a2 = 0.f, a3 = 0.f;
#pragma unroll
    for (int r = 0; r < 16; ++r) {
      a0 += ts[r] * brow[r].x;
      a1 += ts[r] * brow[r].y;
      a2 += ts[r] * brow[r].z;
      a3 += ts[r] * brow[r].w;
    }
    const float4 accv = {a0, a1, a2, a3};
    *reinterpret_cast<float4*>(&out[(rbase + rowl) * OUT_F + colbase + cq * 4]) = accv;
  }
}

extern "C" void kernel_launch(void* const* d_in, const int* in_sizes, int n_in,
                              void* d_out, int out_size, void* d_ws, size_t ws_size,
                              hipStream_t stream) {
  const float* x  = (const float*)d_in[0];   // (2,512,4096) f32
  const float* wA = (const float*)d_in[1];   // (32,4096) f32
  const float* wB = (const float*)d_in[2];   // (8192,16) f32
  float* out = (float*)d_out;                // (2,512,12288) f32
  float* Tpart = (float*)d_ws;               // (KS,1024,32) f32 = 2 MB
  float* T = Tpart + (size_t)KS * M_ROWS * R2;  // (1024,32) f32 = 128 KB

  lora_a_kernel<<<dim3(KS, M_ROWS / 16), 256, 0, stream>>>(x, wA, Tpart);
  lora_r_kernel<<<dim3(M_ROWS / 4), 256, 0, stream>>>(Tpart, T, out);
  lora_b_kernel<<<dim3(32, M_ROWS / 32), 256, 0, stream>>>(T, wB, out);
}